// Round 1
// baseline (8550.804 us; speedup 1.0000x reference)
//
#include <hip/hip_runtime.h>
#include <cmath>

#define BATCH 8192
#define BM 128
#define BN 128
#define BK 16

__device__ __forceinline__ float leakyf(float x) { return x > 0.f ? x : 0.01f * x; }

__device__ __forceinline__ const float* partPtr(const float* A0, int K0,
                                                const float* A1, int K1,
                                                const float* A2, int K2,
                                                int m, int k) {
    if (k < K0) return A0 + (size_t)m * K0 + k;
    k -= K0;
    if (k < K1) return A1 + (size_t)m * K1 + k;
    k -= K1;
    return A2 + (size_t)m * K2 + k;
}

// ---------------------------------------------------------------------------
// Plain GEMM with up-to-3-way concatenated A, bias, optional activation.
// C[M,N] = act( [A0|A1|A2] @ W + bias )
// ACT: 0 = none, 1 = leaky(0.01), 2 = clip(-5,5)
// ---------------------------------------------------------------------------
template <int ACT>
__global__ __launch_bounds__(256) void gemm_cat(
    const float* __restrict__ A0, int K0,
    const float* __restrict__ A1, int K1,
    const float* __restrict__ A2, int K2,
    const float* __restrict__ W, const float* __restrict__ bias,
    float* __restrict__ C, int M, int N, int K) {
    __shared__ float As[BK][BM];
    __shared__ float Bs[BK][BN];
    const int tid = threadIdx.x;
    const int m0 = blockIdx.y * BM;
    const int n0 = blockIdx.x * BN;
    const int ty = tid >> 4, tx = tid & 15;

    float acc[8][8];
#pragma unroll
    for (int i = 0; i < 8; ++i)
#pragma unroll
        for (int j = 0; j < 8; ++j) acc[i][j] = 0.f;

    for (int kt = 0; kt < K; kt += BK) {
        // stage A tile: 128 rows x 16 k
#pragma unroll
        for (int i = 0; i < 2; ++i) {
            int c = tid + 256 * i;
            int row = c >> 2;
            int kc = (c & 3) << 2;
            const float* p = partPtr(A0, K0, A1, K1, A2, K2, m0 + row, kt + kc);
            float4 v = *reinterpret_cast<const float4*>(p);
            As[kc + 0][row] = v.x;
            As[kc + 1][row] = v.y;
            As[kc + 2][row] = v.z;
            As[kc + 3][row] = v.w;
        }
        // stage B tile: 16 k x 128 n
#pragma unroll
        for (int i = 0; i < 2; ++i) {
            int c = tid + 256 * i;
            int kr = c >> 5;
            int nc = (c & 31) << 2;
            float4 v = make_float4(0.f, 0.f, 0.f, 0.f);
            if (n0 + nc < N)
                v = *reinterpret_cast<const float4*>(W + (size_t)(kt + kr) * N + n0 + nc);
            *reinterpret_cast<float4*>(&Bs[kr][nc]) = v;
        }
        __syncthreads();
#pragma unroll
        for (int kk = 0; kk < BK; ++kk) {
            float a[8], b[8];
#pragma unroll
            for (int i = 0; i < 8; ++i) a[i] = As[kk][ty * 8 + i];
#pragma unroll
            for (int j = 0; j < 8; ++j) b[j] = Bs[kk][tx * 8 + j];
#pragma unroll
            for (int i = 0; i < 8; ++i)
#pragma unroll
                for (int j = 0; j < 8; ++j) acc[i][j] += a[i] * b[j];
        }
        __syncthreads();
    }

#pragma unroll
    for (int i = 0; i < 8; ++i) {
        int row = m0 + ty * 8 + i;
#pragma unroll
        for (int j = 0; j < 8; ++j) {
            int col = n0 + tx * 8 + j;
            if (col < N) {
                float v = acc[i][j] + bias[col];
                if (ACT == 1) v = leakyf(v);
                if (ACT == 2) v = fminf(fmaxf(v, -5.f), 5.f);
                C[(size_t)row * N + col] = v;
            }
        }
    }
}

// ---------------------------------------------------------------------------
// Soft-MoE GEMM: C[M,N] = act( sum_e coeff[m,e] * ([A0|A1|A2] @ W_e + b_e) )
// Wd: [4, K, N], biasd: [4, N], coeff: [M, 4]
// ---------------------------------------------------------------------------
template <int ACT>
__global__ __launch_bounds__(256) void gemm_moe(
    const float* __restrict__ A0, int K0,
    const float* __restrict__ A1, int K1,
    const float* __restrict__ A2, int K2,
    const float* __restrict__ Wd, const float* __restrict__ biasd,
    const float* __restrict__ coeff,
    float* __restrict__ C, int M, int N, int K) {
    __shared__ float As[BK][BM];
    __shared__ float Bs[BK][BN];
    const int tid = threadIdx.x;
    const int m0 = blockIdx.y * BM;
    const int n0 = blockIdx.x * BN;
    const int ty = tid >> 4, tx = tid & 15;

    float accf[8][8];
#pragma unroll
    for (int i = 0; i < 8; ++i)
#pragma unroll
        for (int j = 0; j < 8; ++j) accf[i][j] = 0.f;

    for (int e = 0; e < 4; ++e) {
        const float* W = Wd + (size_t)e * K * N;
        float acc[8][8];
#pragma unroll
        for (int i = 0; i < 8; ++i)
#pragma unroll
            for (int j = 0; j < 8; ++j) acc[i][j] = 0.f;

        for (int kt = 0; kt < K; kt += BK) {
#pragma unroll
            for (int i = 0; i < 2; ++i) {
                int c = tid + 256 * i;
                int row = c >> 2;
                int kc = (c & 3) << 2;
                const float* p = partPtr(A0, K0, A1, K1, A2, K2, m0 + row, kt + kc);
                float4 v = *reinterpret_cast<const float4*>(p);
                As[kc + 0][row] = v.x;
                As[kc + 1][row] = v.y;
                As[kc + 2][row] = v.z;
                As[kc + 3][row] = v.w;
            }
#pragma unroll
            for (int i = 0; i < 2; ++i) {
                int c = tid + 256 * i;
                int kr = c >> 5;
                int nc = (c & 31) << 2;
                float4 v = make_float4(0.f, 0.f, 0.f, 0.f);
                if (n0 + nc < N)
                    v = *reinterpret_cast<const float4*>(W + (size_t)(kt + kr) * N + n0 + nc);
                *reinterpret_cast<float4*>(&Bs[kr][nc]) = v;
            }
            __syncthreads();
#pragma unroll
            for (int kk = 0; kk < BK; ++kk) {
                float a[8], b[8];
#pragma unroll
                for (int i = 0; i < 8; ++i) a[i] = As[kk][ty * 8 + i];
#pragma unroll
                for (int j = 0; j < 8; ++j) b[j] = Bs[kk][tx * 8 + j];
#pragma unroll
                for (int i = 0; i < 8; ++i)
#pragma unroll
                    for (int j = 0; j < 8; ++j) acc[i][j] += a[i] * b[j];
            }
            __syncthreads();
        }
        // fold expert e into the final accumulator, scaled per-row
#pragma unroll
        for (int i = 0; i < 8; ++i) {
            float cf = coeff[(size_t)(m0 + ty * 8 + i) * 4 + e];
#pragma unroll
            for (int j = 0; j < 8; ++j) accf[i][j] += cf * acc[i][j];
        }
    }

#pragma unroll
    for (int i = 0; i < 8; ++i) {
        int row = m0 + ty * 8 + i;
        float4 c4 = *reinterpret_cast<const float4*>(&coeff[(size_t)row * 4]);
#pragma unroll
        for (int j = 0; j < 8; ++j) {
            int col = n0 + tx * 8 + j;
            if (col < N) {
                float bm = c4.x * biasd[0 * N + col] + c4.y * biasd[1 * N + col] +
                           c4.z * biasd[2 * N + col] + c4.w * biasd[3 * N + col];
                float v = accf[i][j] + bm;
                if (ACT == 1) v = leakyf(v);
                C[(size_t)row * N + col] = v;
            }
        }
    }
}

// ---------------------------------------------------------------------------
// normalize: xn = clip((x-m)/sqrt(v+1e-4),-5,5); wn same + NaN->0
// ---------------------------------------------------------------------------
__global__ void norm_k(const float* __restrict__ x, const float* __restrict__ w,
                       const float* __restrict__ im, const float* __restrict__ iv,
                       const float* __restrict__ cm, const float* __restrict__ cv,
                       float* __restrict__ xn, float* __restrict__ wn) {
    int idx = blockIdx.x * 256 + threadIdx.x;
    const int totalX = BATCH * 512;
    const int totalW = BATCH * 256;
    if (idx < totalX) {
        int j = idx & 511;
        float v = (x[idx] - im[j]) * rsqrtf(iv[j] + 1e-4f);
        if (v != v) v = 0.f;  // NaN guard (matches clip->NaN->0 path)
        v = fminf(fmaxf(v, -5.f), 5.f);
        xn[idx] = v;
    } else if (idx < totalX + totalW) {
        int k = idx - totalX;
        int j = k & 255;
        float v = (w[k] - cm[j]) * rsqrtf(cv[j] + 1e-4f);
        if (v != v) v = 0.f;
        v = fminf(fmaxf(v, -5.f), 5.f);
        wn[k] = v;
    }
}

// z = mu + eps * exp(0.5 * log_var)   (log_var already clipped)
__global__ void reparam_k(const float* __restrict__ mu, const float* __restrict__ lv,
                          const float* __restrict__ eps, float* __restrict__ z) {
    int idx = blockIdx.x * 256 + threadIdx.x;
    if (idx < BATCH * 128) z[idx] = mu[idx] + eps[idx] * expf(0.5f * lv[idx]);
}

// logits = g1 @ w2 + b2  (64 -> 4), then softmax over 4
__global__ void gate_sm_k(const float* __restrict__ g1, const float* __restrict__ w2,
                          const float* __restrict__ b2, float* __restrict__ coeff) {
    int r = blockIdx.x * 256 + threadIdx.x;
    if (r >= BATCH) return;
    float l0 = b2[0], l1 = b2[1], l2 = b2[2], l3 = b2[3];
    const float* row = g1 + (size_t)r * 64;
#pragma unroll
    for (int k = 0; k < 64; ++k) {
        float gv = row[k];
        l0 += gv * w2[k * 4 + 0];
        l1 += gv * w2[k * 4 + 1];
        l2 += gv * w2[k * 4 + 2];
        l3 += gv * w2[k * 4 + 3];
    }
    float mx = fmaxf(fmaxf(l0, l1), fmaxf(l2, l3));
    float e0 = expf(l0 - mx), e1 = expf(l1 - mx), e2 = expf(l2 - mx), e3 = expf(l3 - mx);
    float s = 1.f / (e0 + e1 + e2 + e3);
    float4 out = make_float4(e0 * s, e1 * s, e2 * s, e3 * s);
    *reinterpret_cast<float4*>(coeff + (size_t)r * 4) = out;
}

extern "C" void kernel_launch(void* const* d_in, const int* in_sizes, int n_in,
                              void* d_out, int out_size, void* d_ws, size_t ws_size,
                              hipStream_t stream) {
    const float* x    = (const float*)d_in[0];
    const float* w    = (const float*)d_in[1];
    const float* epsv = (const float*)d_in[2];
    const float* rim  = (const float*)d_in[3];
    const float* riv  = (const float*)d_in[4];
    const float* rcm  = (const float*)d_in[5];
    const float* rcv  = (const float*)d_in[6];
    const float* ew0 = (const float*)d_in[7];  const float* eb0 = (const float*)d_in[8];
    const float* ew1 = (const float*)d_in[9];  const float* eb1 = (const float*)d_in[10];
    const float* ew2 = (const float*)d_in[11]; const float* eb2 = (const float*)d_in[12];
    const float* ew3 = (const float*)d_in[13]; const float* eb3 = (const float*)d_in[14];
    const float* muw = (const float*)d_in[15]; const float* mub = (const float*)d_in[16];
    const float* lvw = (const float*)d_in[17]; const float* lvb = (const float*)d_in[18];
    const float* gw0 = (const float*)d_in[19]; const float* gb0 = (const float*)d_in[20];
    const float* gw1 = (const float*)d_in[21]; const float* gb1 = (const float*)d_in[22];
    const float* gw2 = (const float*)d_in[23]; const float* gb2 = (const float*)d_in[24];
    const float* dw0 = (const float*)d_in[25]; const float* db0 = (const float*)d_in[26];
    const float* dw1 = (const float*)d_in[27]; const float* db1 = (const float*)d_in[28];
    const float* dw2 = (const float*)d_in[29]; const float* db2 = (const float*)d_in[30];
    const float* dw3 = (const float*)d_in[31]; const float* db3 = (const float*)d_in[32];
    const float* dw4 = (const float*)d_in[33]; const float* db4 = (const float*)d_in[34];

    float* out    = (float*)d_out;
    float* z_out  = out;                          // [B,128]
    float* y_out  = out + (size_t)BATCH * 128;    // [B,512]
    float* mu_out = out + (size_t)BATCH * 640;    // [B,128]
    float* lv_out = out + (size_t)BATCH * 768;    // [B,128]

    float* ws = (float*)d_ws;
    float* xn = ws;                                // [B,512]
    float* wn = xn + (size_t)BATCH * 512;          // [B,256]
    float* h0 = wn + (size_t)BATCH * 256;          // [B,1024]
    float* h1 = h0 + (size_t)BATCH * 1024;         // [B,1024]
    float* g0 = h1 + (size_t)BATCH * 1024;         // [B,64]
    float* g1 = g0 + (size_t)BATCH * 64;           // [B,64]
    float* cf = g1 + (size_t)BATCH * 64;           // [B,4]

    dim3 blk(256);
    auto grid2 = [](int N) { return dim3((N + BN - 1) / BN, BATCH / BM); };

    int totalN = BATCH * (512 + 256);
    norm_k<<<dim3((totalN + 255) / 256), blk, 0, stream>>>(x, w, rim, riv, rcm, rcv, xn, wn);

    // encoder (no inter-layer activation; last layer stores leaky(h))
    gemm_cat<0><<<grid2(1024), blk, 0, stream>>>(xn, 512, wn, 256, nullptr, 0, ew0, eb0, h0, BATCH, 1024, 768);
    gemm_cat<0><<<grid2(1024), blk, 0, stream>>>(wn, 256, h0, 1024, nullptr, 0, ew1, eb1, h1, BATCH, 1024, 1280);
    gemm_cat<0><<<grid2(1024), blk, 0, stream>>>(wn, 256, h1, 1024, nullptr, 0, ew2, eb2, h0, BATCH, 1024, 1280);
    gemm_cat<1><<<grid2(1024), blk, 0, stream>>>(wn, 256, h0, 1024, nullptr, 0, ew3, eb3, h1, BATCH, 1024, 1280);

    // heads: mu (none), log_var (clip +/-5)
    gemm_cat<0><<<grid2(128), blk, 0, stream>>>(h1, 1024, nullptr, 0, nullptr, 0, muw, mub, mu_out, BATCH, 128, 1024);
    gemm_cat<2><<<grid2(128), blk, 0, stream>>>(h1, 1024, nullptr, 0, nullptr, 0, lvw, lvb, lv_out, BATCH, 128, 1024);

    reparam_k<<<dim3((BATCH * 128 + 255) / 256), blk, 0, stream>>>(mu_out, lv_out, epsv, z_out);

    // gate
    gemm_cat<1><<<grid2(64), blk, 0, stream>>>(z_out, 128, wn, 256, nullptr, 0, gw0, gb0, g0, BATCH, 64, 384);
    gemm_cat<1><<<grid2(64), blk, 0, stream>>>(g0, 64, nullptr, 0, nullptr, 0, gw1, gb1, g1, BATCH, 64, 64);
    gate_sm_k<<<dim3((BATCH + 255) / 256), blk, 0, stream>>>(g1, gw2, gb2, cf);

    // decoder (soft-MoE), ping-pong through h0/h1 (free after heads)
    gemm_moe<1><<<grid2(1024), blk, 0, stream>>>(z_out, 128, wn, 256, nullptr, 0, dw0, db0, cf, h0, BATCH, 1024, 384);
    gemm_moe<1><<<grid2(1024), blk, 0, stream>>>(z_out, 128, wn, 256, h0, 1024, dw1, db1, cf, h1, BATCH, 1024, 1408);
    gemm_moe<1><<<grid2(1024), blk, 0, stream>>>(z_out, 128, wn, 256, h1, 1024, dw2, db2, cf, h0, BATCH, 1024, 1408);
    gemm_moe<1><<<grid2(1024), blk, 0, stream>>>(z_out, 128, wn, 256, h0, 1024, dw3, db3, cf, h1, BATCH, 1024, 1408);
    gemm_moe<0><<<grid2(512),  blk, 0, stream>>>(z_out, 128, wn, 256, h1, 1024, dw4, db4, cf, y_out, BATCH, 512, 1408);
}

// Round 2
// 1297.903 us; speedup vs baseline: 6.5882x; 6.5882x over previous
//
#include <hip/hip_runtime.h>

#define BATCH 8192

typedef __bf16 bf16x8 __attribute__((ext_vector_type(8)));
typedef float f32x4 __attribute__((ext_vector_type(4)));

__device__ __forceinline__ float leakyf(float x) { return x > 0.f ? x : 0.01f * x; }

__device__ __forceinline__ short f2bf(float f) {
    union { float f; unsigned u; } v; v.f = f;
    unsigned r = v.u + 0x7fffu + ((v.u >> 16) & 1u);  // RNE
    return (short)(r >> 16);
}
__device__ __forceinline__ float bf2f(short s) {
    union { unsigned u; float f; } v; v.u = ((unsigned)(unsigned short)s) << 16;
    return v.f;
}

// ---------------------------------------------------------------------------
// transpose + fp32->bf16 convert: out[c*ldo + r] = bf16(in[r*C + c])
// R, C multiples of 32. block (32,8), grid (C/32, R/32).
// ---------------------------------------------------------------------------
__global__ __launch_bounds__(256) void transconv_k(const float* __restrict__ in,
                                                   short* __restrict__ out,
                                                   int R, int C, int ldo) {
    __shared__ float t[32][33];
    const int r0 = blockIdx.y * 32, c0 = blockIdx.x * 32;
    const int tx = threadIdx.x, ty = threadIdx.y;
#pragma unroll
    for (int i = 0; i < 4; ++i)
        t[ty * 4 + i][tx] = in[(size_t)(r0 + ty * 4 + i) * C + c0 + tx];
    __syncthreads();
#pragma unroll
    for (int i = 0; i < 4; ++i)
        out[(size_t)(c0 + ty * 4 + i) * ldo + r0 + tx] = f2bf(t[tx][ty * 4 + i]);
}

// ---------------------------------------------------------------------------
// bf16 MFMA GEMM, m97-style: BMxBN tile, BK=64, 4 waves (2x2), linear LDS,
// global_load_lds width-16 staging, 2 barriers per K-step.
//   A:  [M][lda] bf16 (cat buffer; logical K columns used starting at col 0)
//   Bt: [N][ldb] bf16 (weights transposed; MoE: expert e at row offset e*K)
// EPI: 0 = +bias -> bf16 out       1 = +bias, leaky -> bf16 out
//      2 = heads (mu|lv combined, N=256): col<128 -> f32 Cf (+bias);
//          col>=128 -> clip(+bias2) -> f32 Cf2
//      3 = MoE: accf = sum_e coeff_e * (A@W_e); + coeff@b; leaky -> bf16 out
//      4 = MoE, no act -> f32 Cf
// ---------------------------------------------------------------------------
template <int BM, int BN, int EPI>
__global__ __launch_bounds__(256) void mm_k(
    const short* __restrict__ A, int lda,
    const short* __restrict__ Bt, int ldb,
    const float* __restrict__ bias, const float* __restrict__ bias2,
    const float* __restrict__ coeff,
    short* __restrict__ Cb, float* __restrict__ Cf, float* __restrict__ Cf2,
    int ldc, int N, int K) {
    constexpr bool MOE = (EPI == 3 || EPI == 4);
    constexpr int WM = BM / 2, WN = BN / 2;
    constexpr int FM = WM / 16, FN = WN / 16;
    __shared__ short As[BM * 64];
    __shared__ short Bs[BN * 64];
    const int tid = threadIdx.x;
    const int wave = tid >> 6, lane = tid & 63;
    const int wm = wave >> 1, wq = wave & 1;
    const int m0 = blockIdx.y * BM, n0 = blockIdx.x * BN;
    const int srow = lane >> 3;          // row within 8-row staging chunk
    const int scol = (lane & 7) << 3;    // short offset within 128B row
    const int l15 = lane & 15;
    const int khalf = (lane >> 4) << 3;  // k-slice base within 32-wide K step

    f32x4 acc[FM][FN];
    f32x4 accf[FM][FN];
    const f32x4 z4 = {0.f, 0.f, 0.f, 0.f};
    if constexpr (MOE) {
#pragma unroll
        for (int i = 0; i < FM; ++i)
#pragma unroll
            for (int j = 0; j < FN; ++j) accf[i][j] = z4;
    }

    constexpr int NE = MOE ? 4 : 1;
#pragma unroll 1
    for (int e = 0; e < NE; ++e) {
        const short* Be = Bt + (size_t)e * K;  // expert column-group within Bt row
#pragma unroll
        for (int i = 0; i < FM; ++i)
#pragma unroll
            for (int j = 0; j < FN; ++j) acc[i][j] = z4;

        for (int kt = 0; kt < K; kt += 64) {
#pragma unroll
            for (int it = 0; it < BM / 32; ++it) {
                int chunk = it * 4 + wave;
                int row = chunk * 8 + srow;
                const short* g = A + (size_t)(m0 + row) * lda + kt + scol;
                __builtin_amdgcn_global_load_lds(
                    (const __attribute__((address_space(1))) void*)g,
                    (__attribute__((address_space(3))) void*)(As + chunk * 512),
                    16, 0, 0);
            }
#pragma unroll
            for (int it = 0; it < BN / 32; ++it) {
                int chunk = it * 4 + wave;
                int row = chunk * 8 + srow;
                const short* g = Be + (size_t)(n0 + row) * ldb + kt + scol;
                __builtin_amdgcn_global_load_lds(
                    (const __attribute__((address_space(1))) void*)g,
                    (__attribute__((address_space(3))) void*)(Bs + chunk * 512),
                    16, 0, 0);
            }
            __syncthreads();
#pragma unroll
            for (int kk = 0; kk < 2; ++kk) {
                bf16x8 a[FM], b[FN];
#pragma unroll
                for (int i = 0; i < FM; ++i)
                    a[i] = *(const bf16x8*)&As[(wm * WM + i * 16 + l15) * 64 + kk * 32 + khalf];
#pragma unroll
                for (int j = 0; j < FN; ++j)
                    b[j] = *(const bf16x8*)&Bs[(wq * WN + j * 16 + l15) * 64 + kk * 32 + khalf];
#pragma unroll
                for (int i = 0; i < FM; ++i)
#pragma unroll
                    for (int j = 0; j < FN; ++j)
                        acc[i][j] = __builtin_amdgcn_mfma_f32_16x16x32_bf16(
                            a[i], b[j], acc[i][j], 0, 0, 0);
            }
            __syncthreads();
        }
        if constexpr (MOE) {
#pragma unroll
            for (int i = 0; i < FM; ++i) {
                int rbase = m0 + wm * WM + i * 16 + ((lane >> 4) << 2);
#pragma unroll
                for (int r = 0; r < 4; ++r) {
                    float ce = coeff[(size_t)(rbase + r) * 4 + e];
#pragma unroll
                    for (int j = 0; j < FN; ++j) accf[i][j][r] += ce * acc[i][j][r];
                }
            }
        }
    }

    // epilogue: D layout col=lane&15, row=(lane>>4)*4+reg
#pragma unroll
    for (int i = 0; i < FM; ++i) {
#pragma unroll
        for (int r = 0; r < 4; ++r) {
            int row = m0 + wm * WM + i * 16 + ((lane >> 4) << 2) + r;
#pragma unroll
            for (int j = 0; j < FN; ++j) {
                int col = n0 + wq * WN + j * 16 + l15;
                float v = MOE ? accf[i][j][r] : acc[i][j][r];
                if constexpr (EPI == 0) {
                    v += bias[col];
                    Cb[(size_t)row * ldc + col] = f2bf(v);
                } else if constexpr (EPI == 1) {
                    v = leakyf(v + bias[col]);
                    Cb[(size_t)row * ldc + col] = f2bf(v);
                } else if constexpr (EPI == 2) {
                    if (col < 128) {
                        Cf[(size_t)row * 128 + col] = v + bias[col];
                    } else {
                        float u = v + bias2[col - 128];
                        u = fminf(fmaxf(u, -5.f), 5.f);
                        Cf2[(size_t)row * 128 + (col - 128)] = u;
                    }
                } else {
                    const float* c4 = coeff + (size_t)row * 4;
                    v += c4[0] * bias[col] + c4[1] * bias[N + col] +
                         c4[2] * bias[2 * N + col] + c4[3] * bias[3 * N + col];
                    if constexpr (EPI == 3) {
                        Cb[(size_t)row * ldc + col] = f2bf(leakyf(v));
                    } else {
                        Cf[(size_t)row * ldc + col] = v;
                    }
                }
            }
        }
    }
}

// ---------------------------------------------------------------------------
// normalize + scatter bf16 into cat buffers
// ---------------------------------------------------------------------------
__global__ __launch_bounds__(256) void norm_k(
    const float* __restrict__ x, const float* __restrict__ w,
    const float* __restrict__ im, const float* __restrict__ iv,
    const float* __restrict__ cm, const float* __restrict__ cv,
    short* __restrict__ enc0, short* __restrict__ encA,
    short* __restrict__ encB, short* __restrict__ dec0) {
    int idx = blockIdx.x * 256 + threadIdx.x;
    const int TX = BATCH * 512;
    if (idx < TX) {
        int b = idx >> 9, j = idx & 511;
        float v = (x[idx] - im[j]) * rsqrtf(iv[j] + 1e-4f);
        v = fminf(fmaxf(v, -5.f), 5.f);
        enc0[(size_t)b * 768 + j] = f2bf(v);
    } else {
        int k = idx - TX;
        if (k < BATCH * 256) {
            int b = k >> 8, j = k & 255;
            float v = (w[k] - cm[j]) * rsqrtf(cv[j] + 1e-4f);
            if (v != v) v = 0.f;  // isnan -> 0 (wn only)
            v = fminf(fmaxf(v, -5.f), 5.f);
            short s = f2bf(v);
            enc0[(size_t)b * 768 + 512 + j] = s;
            encA[(size_t)b * 1280 + j] = s;
            encB[(size_t)b * 1280 + j] = s;
            dec0[(size_t)b * 384 + 128 + j] = s;
        }
    }
}

__global__ __launch_bounds__(256) void reparam_k(
    const float* __restrict__ mu, const float* __restrict__ lv,
    const float* __restrict__ eps, float* __restrict__ z, short* __restrict__ dec0) {
    int idx = blockIdx.x * 256 + threadIdx.x;
    if (idx >= BATCH * 128) return;
    float zv = mu[idx] + eps[idx] * expf(0.5f * lv[idx]);
    z[idx] = zv;
    int b = idx >> 7, j = idx & 127;
    dec0[(size_t)b * 384 + j] = f2bf(zv);
}

__global__ __launch_bounds__(256) void fill_dec_k(const short* __restrict__ dec0,
                                                  short* __restrict__ decA,
                                                  short* __restrict__ decB) {
    int idx = blockIdx.x * 256 + threadIdx.x;
    if (idx >= BATCH * 384) return;
    int b = idx / 384, c = idx - b * 384;
    short s = dec0[idx];
    decA[(size_t)b * 1408 + c] = s;
    decB[(size_t)b * 1408 + c] = s;
}

__global__ __launch_bounds__(256) void gate_sm_k(const short* __restrict__ g1,
                                                 const float* __restrict__ w2,
                                                 const float* __restrict__ b2,
                                                 float* __restrict__ coeff) {
    int r = blockIdx.x * 256 + threadIdx.x;
    if (r >= BATCH) return;
    float l0 = b2[0], l1 = b2[1], l2 = b2[2], l3 = b2[3];
    const short* row = g1 + (size_t)r * 64;
#pragma unroll
    for (int k = 0; k < 64; ++k) {
        float gv = bf2f(row[k]);
        l0 += gv * w2[k * 4 + 0];
        l1 += gv * w2[k * 4 + 1];
        l2 += gv * w2[k * 4 + 2];
        l3 += gv * w2[k * 4 + 3];
    }
    float mx = fmaxf(fmaxf(l0, l1), fmaxf(l2, l3));
    float e0 = expf(l0 - mx), e1 = expf(l1 - mx), e2 = expf(l2 - mx), e3 = expf(l3 - mx);
    float s = 1.f / (e0 + e1 + e2 + e3);
    float4 outv = make_float4(e0 * s, e1 * s, e2 * s, e3 * s);
    *reinterpret_cast<float4*>(coeff + (size_t)r * 4) = outv;
}

extern "C" void kernel_launch(void* const* d_in, const int* in_sizes, int n_in,
                              void* d_out, int out_size, void* d_ws, size_t ws_size,
                              hipStream_t stream) {
    const float* x    = (const float*)d_in[0];
    const float* w    = (const float*)d_in[1];
    const float* epsv = (const float*)d_in[2];
    const float* rim  = (const float*)d_in[3];
    const float* riv  = (const float*)d_in[4];
    const float* rcm  = (const float*)d_in[5];
    const float* rcv  = (const float*)d_in[6];
    const float* ew0 = (const float*)d_in[7];  const float* eb0 = (const float*)d_in[8];
    const float* ew1 = (const float*)d_in[9];  const float* eb1 = (const float*)d_in[10];
    const float* ew2 = (const float*)d_in[11]; const float* eb2 = (const float*)d_in[12];
    const float* ew3 = (const float*)d_in[13]; const float* eb3 = (const float*)d_in[14];
    const float* muw = (const float*)d_in[15]; const float* mub = (const float*)d_in[16];
    const float* lvw = (const float*)d_in[17]; const float* lvb = (const float*)d_in[18];
    const float* gw0 = (const float*)d_in[19]; const float* gb0 = (const float*)d_in[20];
    const float* gw1 = (const float*)d_in[21]; const float* gb1 = (const float*)d_in[22];
    const float* gw2 = (const float*)d_in[23]; const float* gb2 = (const float*)d_in[24];
    const float* dw0 = (const float*)d_in[25]; const float* db0 = (const float*)d_in[26];
    const float* dw1 = (const float*)d_in[27]; const float* db1 = (const float*)d_in[28];
    const float* dw2 = (const float*)d_in[29]; const float* db2 = (const float*)d_in[30];
    const float* dw3 = (const float*)d_in[31]; const float* db3 = (const float*)d_in[32];
    const float* dw4 = (const float*)d_in[33]; const float* db4 = (const float*)d_in[34];

    float* out    = (float*)d_out;
    float* z_out  = out;                          // [B,128]
    float* y_out  = out + (size_t)BATCH * 128;    // [B,512]
    float* mu_out = out + (size_t)BATCH * 640;    // [B,128]
    float* lv_out = out + (size_t)BATCH * 768;    // [B,128]

    // ---- workspace carve (≈117 MB, phase-aliased) ----
    char* cur = (char*)d_ws;
    auto alloc = [&](size_t bytes) -> char* {
        char* p = cur;
        cur += (bytes + 255) & ~(size_t)255;
        return p;
    };
    short* ew0t = (short*)alloc((size_t)768 * 1024 * 2);
    short* ew1t = (short*)alloc((size_t)1280 * 1024 * 2);
    short* ew2t = (short*)alloc((size_t)1280 * 1024 * 2);
    short* ew3t = (short*)alloc((size_t)1280 * 1024 * 2);
    short* hdWt = (short*)alloc((size_t)256 * 1024 * 2);   // rows 0-127 mu, 128-255 lv
    short* gw0t = (short*)alloc((size_t)64 * 384 * 2);
    short* gw1t = (short*)alloc((size_t)64 * 64 * 2);
    short* dw0t = (short*)alloc((size_t)1024 * 1536 * 2);
    short* dw1t = (short*)alloc((size_t)1024 * 5632 * 2);
    short* dw2t = (short*)alloc((size_t)1024 * 5632 * 2);
    short* dw3t = (short*)alloc((size_t)1024 * 5632 * 2);
    short* dw4t = (short*)alloc((size_t)512 * 5632 * 2);
    short* dec0 = (short*)alloc((size_t)BATCH * 384 * 2);  // [z|wn]
    short* g0   = (short*)alloc((size_t)BATCH * 64 * 2);
    short* g1   = (short*)alloc((size_t)BATCH * 64 * 2);
    float* cf   = (float*)alloc((size_t)BATCH * 4 * 4);
    // phase-shared region: encoder {enc0|encA|encB(=hl)} then decoder {decA|decB}
    char* region = cur;
    short* enc0 = (short*)region;                                        // [B,768]
    short* encA = (short*)(region + ((size_t)BATCH * 768 * 2 + 255 & ~(size_t)255));   // [B,1280]
    short* encB = (short*)((char*)encA + ((size_t)BATCH * 1280 * 2 + 255 & ~(size_t)255)); // [B,1280]
    short* hl   = encB;                                                  // [B,1024], after encB dead
    short* decA = (short*)region;                                        // [B,1408]
    short* decB = (short*)(region + ((size_t)BATCH * 1408 * 2 + 255 & ~(size_t)255));  // [B,1408]

    dim3 blk(256);
    dim3 tblk(32, 8);

    // ---- weight transpose+convert (runs every launch; ~27 µs of traffic) ----
    transconv_k<<<dim3(1024 / 32, 768 / 32), tblk, 0, stream>>>(ew0, ew0t, 768, 1024, 768);
    transconv_k<<<dim3(1024 / 32, 1280 / 32), tblk, 0, stream>>>(ew1, ew1t, 1280, 1024, 1280);
    transconv_k<<<dim3(1024 / 32, 1280 / 32), tblk, 0, stream>>>(ew2, ew2t, 1280, 1024, 1280);
    transconv_k<<<dim3(1024 / 32, 1280 / 32), tblk, 0, stream>>>(ew3, ew3t, 1280, 1024, 1280);
    transconv_k<<<dim3(128 / 32, 1024 / 32), tblk, 0, stream>>>(muw, hdWt, 1024, 128, 1024);
    transconv_k<<<dim3(128 / 32, 1024 / 32), tblk, 0, stream>>>(lvw, hdWt + (size_t)128 * 1024, 1024, 128, 1024);
    transconv_k<<<dim3(64 / 32, 384 / 32), tblk, 0, stream>>>(gw0, gw0t, 384, 64, 384);
    transconv_k<<<dim3(64 / 32, 64 / 32), tblk, 0, stream>>>(gw1, gw1t, 64, 64, 64);
    transconv_k<<<dim3(1024 / 32, 1536 / 32), tblk, 0, stream>>>(dw0, dw0t, 1536, 1024, 1536);
    transconv_k<<<dim3(1024 / 32, 5632 / 32), tblk, 0, stream>>>(dw1, dw1t, 5632, 1024, 5632);
    transconv_k<<<dim3(1024 / 32, 5632 / 32), tblk, 0, stream>>>(dw2, dw2t, 5632, 1024, 5632);
    transconv_k<<<dim3(1024 / 32, 5632 / 32), tblk, 0, stream>>>(dw3, dw3t, 5632, 1024, 5632);
    transconv_k<<<dim3(512 / 32, 5632 / 32), tblk, 0, stream>>>(dw4, dw4t, 5632, 512, 5632);

    // ---- normalize into cat buffers ----
    norm_k<<<dim3(BATCH * 768 / 256), blk, 0, stream>>>(x, w, rim, riv, rcm, rcv,
                                                        enc0, encA, encB, dec0);

    // ---- encoder (bf16 MFMA) ----
    dim3 gEnc(1024 / 128, BATCH / 128);
    mm_k<128, 128, 0><<<gEnc, blk, 0, stream>>>(enc0, 768, ew0t, 768, eb0, nullptr, nullptr,
                                                encA + 256, nullptr, nullptr, 1280, 1024, 768);
    mm_k<128, 128, 0><<<gEnc, blk, 0, stream>>>(encA, 1280, ew1t, 1280, eb1, nullptr, nullptr,
                                                encB + 256, nullptr, nullptr, 1280, 1024, 1280);
    mm_k<128, 128, 0><<<gEnc, blk, 0, stream>>>(encB, 1280, ew2t, 1280, eb2, nullptr, nullptr,
                                                encA + 256, nullptr, nullptr, 1280, 1024, 1280);
    mm_k<128, 128, 1><<<gEnc, blk, 0, stream>>>(encA, 1280, ew3t, 1280, eb3, nullptr, nullptr,
                                                hl, nullptr, nullptr, 1024, 1024, 1280);

    // ---- heads: mu | clip(lv), fused N=256 ----
    mm_k<64, 128, 2><<<dim3(2, BATCH / 64), blk, 0, stream>>>(hl, 1024, hdWt, 1024, mub, lvb,
                                                              nullptr, nullptr, mu_out, lv_out,
                                                              0, 256, 1024);

    reparam_k<<<dim3(BATCH * 128 / 256), blk, 0, stream>>>(mu_out, lv_out, epsv, z_out, dec0);
    fill_dec_k<<<dim3(BATCH * 384 / 256), blk, 0, stream>>>(dec0, decA, decB);

    // ---- gate ----
    mm_k<64, 64, 1><<<dim3(1, BATCH / 64), blk, 0, stream>>>(dec0, 384, gw0t, 384, gb0, nullptr,
                                                             nullptr, g0, nullptr, nullptr,
                                                             64, 64, 384);
    mm_k<64, 64, 1><<<dim3(1, BATCH / 64), blk, 0, stream>>>(g0, 64, gw1t, 64, gb1, nullptr,
                                                             nullptr, g1, nullptr, nullptr,
                                                             64, 64, 64);
    gate_sm_k<<<dim3(BATCH / 256), blk, 0, stream>>>(g1, gw2, gb2, cf);

    // ---- decoder (soft-MoE, in-kernel expert loop) ----
    dim3 gDec(1024 / 128, BATCH / 128);
    mm_k<128, 128, 3><<<gDec, blk, 0, stream>>>(dec0, 384, dw0t, 1536, db0, nullptr, cf,
                                                decA + 384, nullptr, nullptr, 1408, 1024, 384);
    mm_k<128, 128, 3><<<gDec, blk, 0, stream>>>(decA, 1408, dw1t, 5632, db1, nullptr, cf,
                                                decB + 384, nullptr, nullptr, 1408, 1024, 1408);
    mm_k<128, 128, 3><<<gDec, blk, 0, stream>>>(decB, 1408, dw2t, 5632, db2, nullptr, cf,
                                                decA + 384, nullptr, nullptr, 1408, 1024, 1408);
    mm_k<128, 128, 3><<<gDec, blk, 0, stream>>>(decA, 1408, dw3t, 5632, db3, nullptr, cf,
                                                decB + 384, nullptr, nullptr, 1408, 1024, 1408);
    mm_k<128, 128, 4><<<dim3(512 / 128, BATCH / 128), blk, 0, stream>>>(
        decB, 1408, dw4t, 5632, db4, nullptr, cf, nullptr, y_out, nullptr, 512, 512, 1408);
}

// Round 3
// 1165.248 us; speedup vs baseline: 7.3382x; 1.1138x over previous
//
#include <hip/hip_runtime.h>

#define BATCH 8192

typedef __bf16 bf16x8 __attribute__((ext_vector_type(8)));
typedef float f32x4 __attribute__((ext_vector_type(4)));

__device__ __forceinline__ float leakyf(float x) { return x > 0.f ? x : 0.01f * x; }

__device__ __forceinline__ short f2bf(float f) {
    union { float f; unsigned u; } v; v.f = f;
    unsigned r = v.u + 0x7fffu + ((v.u >> 16) & 1u);  // RNE
    return (short)(r >> 16);
}
__device__ __forceinline__ float bf2f(short s) {
    union { unsigned u; float f; } v; v.u = ((unsigned)(unsigned short)s) << 16;
    return v.f;
}

// ---------------------------------------------------------------------------
// transpose + fp32->bf16 convert: out[c*ldo + r] = bf16(in[r*C + c])
// ---------------------------------------------------------------------------
__global__ __launch_bounds__(256) void transconv_k(const float* __restrict__ in,
                                                   short* __restrict__ out,
                                                   int R, int C, int ldo) {
    __shared__ float t[32][33];
    const int r0 = blockIdx.y * 32, c0 = blockIdx.x * 32;
    const int tx = threadIdx.x, ty = threadIdx.y;
#pragma unroll
    for (int i = 0; i < 4; ++i)
        t[ty * 4 + i][tx] = in[(size_t)(r0 + ty * 4 + i) * C + c0 + tx];
    __syncthreads();
#pragma unroll
    for (int i = 0; i < 4; ++i)
        out[(size_t)(c0 + ty * 4 + i) * ldo + r0 + tx] = f2bf(t[tx][ty * 4 + i]);
}

// ---------------------------------------------------------------------------
// MoE weight transpose with row permutation for the grouped-A' layout:
// input rows r = e*1408 + k (e<4, k<1408); output col
//   r' = k<384 ? e*384+k : 1536 + e*1024 + (k-384);   ldo = 5632
// 32-row runs never straddle a segment (384, 1408 are multiples of 32).
// ---------------------------------------------------------------------------
__global__ __launch_bounds__(256) void transconv_moe_k(const float* __restrict__ in,
                                                       short* __restrict__ out, int C) {
    __shared__ float t[32][33];
    const int r0 = blockIdx.y * 32, c0 = blockIdx.x * 32;
    const int tx = threadIdx.x, ty = threadIdx.y;
#pragma unroll
    for (int i = 0; i < 4; ++i)
        t[ty * 4 + i][tx] = in[(size_t)(r0 + ty * 4 + i) * C + c0 + tx];
    __syncthreads();
    const int e = r0 / 1408, k = r0 - e * 1408;
    const int rp0 = (k < 384) ? (e * 384 + k) : (1536 + e * 1024 + (k - 384));
#pragma unroll
    for (int i = 0; i < 4; ++i)
        out[(size_t)(c0 + ty * 4 + i) * 5632 + rp0 + tx] = f2bf(t[tx][ty * 4 + i]);
}

// ---------------------------------------------------------------------------
// bf16 MFMA GEMM, m97-style, + XCD-chunked block swizzle.
// EPI: 0 = +bias -> bf16      1 = +bias, leaky -> bf16
//      2 = heads mu|lv (N=256): col<128 -> f32 Cf; col>=128 clip -> f32 Cf2
//      3 = MoE expert loop, leaky -> bf16 (SAFE path)
//      4 = MoE expert loop, no act -> f32 (SAFE path)
//      5 = +coeff@bias, leaky, write 4 coeff-scaled bf16 copies at e*1024 (FAST)
//      6 = +coeff@bias, no act -> f32 (FAST last layer)
// ---------------------------------------------------------------------------
template <int BM, int BN, int EPI>
__global__ __launch_bounds__(256) void mm_k(
    const short* __restrict__ A, int lda,
    const short* __restrict__ Bt, int ldb,
    const float* __restrict__ bias, const float* __restrict__ bias2,
    const float* __restrict__ coeff,
    short* __restrict__ Cb, float* __restrict__ Cf, float* __restrict__ Cf2,
    int ldc, int N, int K) {
    constexpr bool MOE = (EPI == 3 || EPI == 4);
    constexpr int WM = BM / 2, WN = BN / 2;
    constexpr int FM = WM / 16, FN = WN / 16;
    __shared__ short As[BM * 64];
    __shared__ short Bs[BN * 64];
    const int tid = threadIdx.x;
    const int wave = tid >> 6, lane = tid & 63;
    const int wm = wave >> 1, wq = wave & 1;

    // XCD-aware swizzle: contiguous grid chunks per XCD (bijective when nwg%8==0)
    int bx = blockIdx.x, by = blockIdx.y;
    {
        int nwg = gridDim.x * gridDim.y;
        if ((nwg & 7) == 0) {
            int flat = by * gridDim.x + bx;
            int nf = (flat & 7) * (nwg >> 3) + (flat >> 3);
            bx = nf % gridDim.x;
            by = nf / gridDim.x;
        }
    }
    const int m0 = by * BM, n0 = bx * BN;
    const int srow = lane >> 3;
    const int scol = (lane & 7) << 3;
    const int l15 = lane & 15;
    const int khalf = (lane >> 4) << 3;

    f32x4 acc[FM][FN];
    f32x4 accf[MOE ? FM : 1][MOE ? FN : 1];
    const f32x4 z4 = {0.f, 0.f, 0.f, 0.f};
    if constexpr (MOE) {
#pragma unroll
        for (int i = 0; i < FM; ++i)
#pragma unroll
            for (int j = 0; j < FN; ++j) accf[i][j] = z4;
    }

    constexpr int NE = MOE ? 4 : 1;
#pragma unroll 1
    for (int e = 0; e < NE; ++e) {
        const short* Be = Bt + (size_t)e * K;
#pragma unroll
        for (int i = 0; i < FM; ++i)
#pragma unroll
            for (int j = 0; j < FN; ++j) acc[i][j] = z4;

        for (int kt = 0; kt < K; kt += 64) {
#pragma unroll
            for (int it = 0; it < BM / 32; ++it) {
                int chunk = it * 4 + wave;
                int row = chunk * 8 + srow;
                const short* g = A + (size_t)(m0 + row) * lda + kt + scol;
                __builtin_amdgcn_global_load_lds(
                    (const __attribute__((address_space(1))) void*)g,
                    (__attribute__((address_space(3))) void*)(As + chunk * 512),
                    16, 0, 0);
            }
#pragma unroll
            for (int it = 0; it < BN / 32; ++it) {
                int chunk = it * 4 + wave;
                int row = chunk * 8 + srow;
                const short* g = Be + (size_t)(n0 + row) * ldb + kt + scol;
                __builtin_amdgcn_global_load_lds(
                    (const __attribute__((address_space(1))) void*)g,
                    (__attribute__((address_space(3))) void*)(Bs + chunk * 512),
                    16, 0, 0);
            }
            __syncthreads();
#pragma unroll
            for (int kk = 0; kk < 2; ++kk) {
                bf16x8 a[FM], b[FN];
#pragma unroll
                for (int i = 0; i < FM; ++i)
                    a[i] = *(const bf16x8*)&As[(wm * WM + i * 16 + l15) * 64 + kk * 32 + khalf];
#pragma unroll
                for (int j = 0; j < FN; ++j)
                    b[j] = *(const bf16x8*)&Bs[(wq * WN + j * 16 + l15) * 64 + kk * 32 + khalf];
#pragma unroll
                for (int i = 0; i < FM; ++i)
#pragma unroll
                    for (int j = 0; j < FN; ++j)
                        acc[i][j] = __builtin_amdgcn_mfma_f32_16x16x32_bf16(
                            a[i], b[j], acc[i][j], 0, 0, 0);
            }
            __syncthreads();
        }
        if constexpr (MOE) {
#pragma unroll
            for (int i = 0; i < FM; ++i) {
                int rbase = m0 + wm * WM + i * 16 + ((lane >> 4) << 2);
#pragma unroll
                for (int r = 0; r < 4; ++r) {
                    float ce = coeff[(size_t)(rbase + r) * 4 + e];
#pragma unroll
                    for (int j = 0; j < FN; ++j) accf[i][j][r] += ce * acc[i][j][r];
                }
            }
        }
    }

    // epilogue: D layout col=lane&15, row=(lane>>4)*4+reg
#pragma unroll
    for (int i = 0; i < FM; ++i) {
#pragma unroll
        for (int r = 0; r < 4; ++r) {
            int row = m0 + wm * WM + i * 16 + ((lane >> 4) << 2) + r;
#pragma unroll
            for (int j = 0; j < FN; ++j) {
                int col = n0 + wq * WN + j * 16 + l15;
                float v = MOE ? accf[i][j][r] : acc[i][j][r];
                if constexpr (EPI == 0) {
                    v += bias[col];
                    Cb[(size_t)row * ldc + col] = f2bf(v);
                } else if constexpr (EPI == 1) {
                    v = leakyf(v + bias[col]);
                    Cb[(size_t)row * ldc + col] = f2bf(v);
                } else if constexpr (EPI == 2) {
                    if (col < 128) {
                        Cf[(size_t)row * 128 + col] = v + bias[col];
                    } else {
                        float u = v + bias2[col - 128];
                        u = fminf(fmaxf(u, -5.f), 5.f);
                        Cf2[(size_t)row * 128 + (col - 128)] = u;
                    }
                } else if constexpr (EPI == 3) {
                    const float* c4 = coeff + (size_t)row * 4;
                    v += c4[0] * bias[col] + c4[1] * bias[N + col] +
                         c4[2] * bias[2 * N + col] + c4[3] * bias[3 * N + col];
                    Cb[(size_t)row * ldc + col] = f2bf(leakyf(v));
                } else if constexpr (EPI == 4) {
                    const float* c4 = coeff + (size_t)row * 4;
                    v += c4[0] * bias[col] + c4[1] * bias[N + col] +
                         c4[2] * bias[2 * N + col] + c4[3] * bias[3 * N + col];
                    Cf[(size_t)row * ldc + col] = v;
                } else if constexpr (EPI == 5) {
                    const float4 c4 = *reinterpret_cast<const float4*>(coeff + (size_t)row * 4);
                    v += c4.x * bias[col] + c4.y * bias[N + col] +
                         c4.z * bias[2 * N + col] + c4.w * bias[3 * N + col];
                    float a = leakyf(v);
                    Cb[(size_t)row * ldc + 0 * 1024 + col] = f2bf(c4.x * a);
                    Cb[(size_t)row * ldc + 1 * 1024 + col] = f2bf(c4.y * a);
                    Cb[(size_t)row * ldc + 2 * 1024 + col] = f2bf(c4.z * a);
                    Cb[(size_t)row * ldc + 3 * 1024 + col] = f2bf(c4.w * a);
                } else {  // EPI == 6
                    const float4 c4 = *reinterpret_cast<const float4*>(coeff + (size_t)row * 4);
                    v += c4.x * bias[col] + c4.y * bias[N + col] +
                         c4.z * bias[2 * N + col] + c4.w * bias[3 * N + col];
                    Cf[(size_t)row * ldc + col] = v;
                }
            }
        }
    }
}

// ---------------------------------------------------------------------------
// normalize + scatter bf16 into cat buffers
// ---------------------------------------------------------------------------
__global__ __launch_bounds__(256) void norm_k(
    const float* __restrict__ x, const float* __restrict__ w,
    const float* __restrict__ im, const float* __restrict__ iv,
    const float* __restrict__ cm, const float* __restrict__ cv,
    short* __restrict__ enc0, short* __restrict__ encA,
    short* __restrict__ encB, short* __restrict__ dec0) {
    int idx = blockIdx.x * 256 + threadIdx.x;
    const int TX = BATCH * 512;
    if (idx < TX) {
        int b = idx >> 9, j = idx & 511;
        float v = (x[idx] - im[j]) * rsqrtf(iv[j] + 1e-4f);
        v = fminf(fmaxf(v, -5.f), 5.f);
        enc0[(size_t)b * 768 + j] = f2bf(v);
    } else {
        int k = idx - TX;
        if (k < BATCH * 256) {
            int b = k >> 8, j = k & 255;
            float v = (w[k] - cm[j]) * rsqrtf(cv[j] + 1e-4f);
            if (v != v) v = 0.f;  // isnan -> 0 (wn only)
            v = fminf(fmaxf(v, -5.f), 5.f);
            short s = f2bf(v);
            enc0[(size_t)b * 768 + 512 + j] = s;
            encA[(size_t)b * 1280 + j] = s;
            encB[(size_t)b * 1280 + j] = s;
            dec0[(size_t)b * 384 + 128 + j] = s;
        }
    }
}

__global__ __launch_bounds__(256) void reparam_k(
    const float* __restrict__ mu, const float* __restrict__ lv,
    const float* __restrict__ eps, float* __restrict__ z, short* __restrict__ dec0) {
    int idx = blockIdx.x * 256 + threadIdx.x;
    if (idx >= BATCH * 128) return;
    float zv = mu[idx] + eps[idx] * expf(0.5f * lv[idx]);
    z[idx] = zv;
    int b = idx >> 7, j = idx & 127;
    dec0[(size_t)b * 384 + j] = f2bf(zv);
}

// FAST: fill the static coeff-scaled [z|c] region (cols 0..1535) of both A' buffers
__global__ __launch_bounds__(256) void fill_zc_k(const short* __restrict__ dec0,
                                                 const float* __restrict__ cf,
                                                 short* __restrict__ dA,
                                                 short* __restrict__ dB) {
    int idx = blockIdx.x * 256 + threadIdx.x;
    if (idx >= BATCH * 1536) return;
    int b = idx / 1536, c = idx - b * 1536;
    int e = c / 384, k = c - e * 384;
    short s = f2bf(cf[(size_t)b * 4 + e] * bf2f(dec0[(size_t)b * 384 + k]));
    dA[(size_t)b * 5632 + c] = s;
    dB[(size_t)b * 5632 + c] = s;
}

// SAFE: replicate dec0 into the 1408-wide cat buffers
__global__ __launch_bounds__(256) void fill_dec_k(const short* __restrict__ dec0,
                                                  short* __restrict__ decA,
                                                  short* __restrict__ decB) {
    int idx = blockIdx.x * 256 + threadIdx.x;
    if (idx >= BATCH * 384) return;
    int b = idx / 384, c = idx - b * 384;
    short s = dec0[idx];
    decA[(size_t)b * 1408 + c] = s;
    decB[(size_t)b * 1408 + c] = s;
}

__global__ __launch_bounds__(256) void gate_sm_k(const short* __restrict__ g1,
                                                 const float* __restrict__ w2,
                                                 const float* __restrict__ b2,
                                                 float* __restrict__ coeff) {
    int r = blockIdx.x * 256 + threadIdx.x;
    if (r >= BATCH) return;
    float l0 = b2[0], l1 = b2[1], l2 = b2[2], l3 = b2[3];
    const short* row = g1 + (size_t)r * 64;
#pragma unroll
    for (int k = 0; k < 64; ++k) {
        float gv = bf2f(row[k]);
        l0 += gv * w2[k * 4 + 0];
        l1 += gv * w2[k * 4 + 1];
        l2 += gv * w2[k * 4 + 2];
        l3 += gv * w2[k * 4 + 3];
    }
    float mx = fmaxf(fmaxf(l0, l1), fmaxf(l2, l3));
    float e0 = expf(l0 - mx), e1 = expf(l1 - mx), e2 = expf(l2 - mx), e3 = expf(l3 - mx);
    float s = 1.f / (e0 + e1 + e2 + e3);
    float4 outv = make_float4(e0 * s, e1 * s, e2 * s, e3 * s);
    *reinterpret_cast<float4*>(coeff + (size_t)r * 4) = outv;
}

extern "C" void kernel_launch(void* const* d_in, const int* in_sizes, int n_in,
                              void* d_out, int out_size, void* d_ws, size_t ws_size,
                              hipStream_t stream) {
    const float* x    = (const float*)d_in[0];
    const float* w    = (const float*)d_in[1];
    const float* epsv = (const float*)d_in[2];
    const float* rim  = (const float*)d_in[3];
    const float* riv  = (const float*)d_in[4];
    const float* rcm  = (const float*)d_in[5];
    const float* rcv  = (const float*)d_in[6];
    const float* ew0 = (const float*)d_in[7];  const float* eb0 = (const float*)d_in[8];
    const float* ew1 = (const float*)d_in[9];  const float* eb1 = (const float*)d_in[10];
    const float* ew2 = (const float*)d_in[11]; const float* eb2 = (const float*)d_in[12];
    const float* ew3 = (const float*)d_in[13]; const float* eb3 = (const float*)d_in[14];
    const float* muw = (const float*)d_in[15]; const float* mub = (const float*)d_in[16];
    const float* lvw = (const float*)d_in[17]; const float* lvb = (const float*)d_in[18];
    const float* gw0 = (const float*)d_in[19]; const float* gb0 = (const float*)d_in[20];
    const float* gw1 = (const float*)d_in[21]; const float* gb1 = (const float*)d_in[22];
    const float* gw2 = (const float*)d_in[23]; const float* gb2 = (const float*)d_in[24];
    const float* dw0 = (const float*)d_in[25]; const float* db0 = (const float*)d_in[26];
    const float* dw1 = (const float*)d_in[27]; const float* db1 = (const float*)d_in[28];
    const float* dw2 = (const float*)d_in[29]; const float* db2 = (const float*)d_in[30];
    const float* dw3 = (const float*)d_in[31]; const float* db3 = (const float*)d_in[32];
    const float* dw4 = (const float*)d_in[33]; const float* db4 = (const float*)d_in[34];

    float* out    = (float*)d_out;
    float* z_out  = out;                          // [B,128]
    float* y_out  = out + (size_t)BATCH * 128;    // [B,512]
    float* mu_out = out + (size_t)BATCH * 640;    // [B,128]
    float* lv_out = out + (size_t)BATCH * 768;    // [B,128]

    // ---- workspace carve ----
    char* cur = (char*)d_ws;
    auto alloc = [&](size_t bytes) -> char* {
        char* p = cur;
        cur += (bytes + 255) & ~(size_t)255;
        return p;
    };
    auto align256 = [](size_t b) { return (b + 255) & ~(size_t)255; };

    short* ew0t = (short*)alloc((size_t)768 * 1024 * 2);
    short* ew1t = (short*)alloc((size_t)1280 * 1024 * 2);
    short* ew2t = (short*)alloc((size_t)1280 * 1024 * 2);
    short* ew3t = (short*)alloc((size_t)1280 * 1024 * 2);
    short* hdWt = (short*)alloc((size_t)256 * 1024 * 2);   // rows 0-127 mu, 128-255 lv
    short* gw0t = (short*)alloc((size_t)64 * 384 * 2);
    short* gw1t = (short*)alloc((size_t)64 * 64 * 2);
    short* dw0t = (short*)alloc((size_t)1024 * 1536 * 2);
    short* dw1t = (short*)alloc((size_t)1024 * 5632 * 2);
    short* dw2t = (short*)alloc((size_t)1024 * 5632 * 2);
    short* dw3t = (short*)alloc((size_t)1024 * 5632 * 2);
    short* dw4t = (short*)alloc((size_t)512 * 5632 * 2);
    short* dec0 = (short*)alloc((size_t)BATCH * 384 * 2);  // [z|wn]
    short* g0   = (short*)alloc((size_t)BATCH * 64 * 2);
    short* g1   = (short*)alloc((size_t)BATCH * 64 * 2);
    float* cf   = (float*)alloc((size_t)BATCH * 4 * 4);

    char* region = cur;
    const size_t bigA = align256((size_t)BATCH * 5632 * 2);     // 92.3 MB
    const size_t fastNeed = (size_t)(region - (char*)d_ws) + 2 * bigA;
    const bool fast = (ws_size >= fastNeed);

    // encoder buffers (alias the decoder region; encoder finishes before decoder)
    short* enc0 = (short*)region;                                           // [B,768]
    short* encA = (short*)(region + align256((size_t)BATCH * 768 * 2));     // [B,1280]
    short* encB = (short*)((char*)encA + align256((size_t)BATCH * 1280 * 2)); // [B,1280]
    short* hl   = encB;                                                     // [B,1024]
    // FAST decoder A' ping-pong: [B][5632] = [zc(1536) | out-scaled(4096)]
    short* dAp = (short*)region;
    short* dBp = (short*)(region + bigA);
    // SAFE decoder cat buffers
    short* decA = (short*)region;                                           // [B,1408]
    short* decB = (short*)(region + align256((size_t)BATCH * 1408 * 2));    // [B,1408]

    dim3 blk(256);
    dim3 tblk(32, 8);

    // ---- weight transpose+convert ----
    transconv_k<<<dim3(1024 / 32, 768 / 32), tblk, 0, stream>>>(ew0, ew0t, 768, 1024, 768);
    transconv_k<<<dim3(1024 / 32, 1280 / 32), tblk, 0, stream>>>(ew1, ew1t, 1280, 1024, 1280);
    transconv_k<<<dim3(1024 / 32, 1280 / 32), tblk, 0, stream>>>(ew2, ew2t, 1280, 1024, 1280);
    transconv_k<<<dim3(1024 / 32, 1280 / 32), tblk, 0, stream>>>(ew3, ew3t, 1280, 1024, 1280);
    transconv_k<<<dim3(128 / 32, 1024 / 32), tblk, 0, stream>>>(muw, hdWt, 1024, 128, 1024);
    transconv_k<<<dim3(128 / 32, 1024 / 32), tblk, 0, stream>>>(lvw, hdWt + (size_t)128 * 1024, 1024, 128, 1024);
    transconv_k<<<dim3(64 / 32, 384 / 32), tblk, 0, stream>>>(gw0, gw0t, 384, 64, 384);
    transconv_k<<<dim3(64 / 32, 64 / 32), tblk, 0, stream>>>(gw1, gw1t, 64, 64, 64);
    transconv_k<<<dim3(1024 / 32, 1536 / 32), tblk, 0, stream>>>(dw0, dw0t, 1536, 1024, 1536);
    if (fast) {
        transconv_moe_k<<<dim3(1024 / 32, 5632 / 32), tblk, 0, stream>>>(dw1, dw1t, 1024);
        transconv_moe_k<<<dim3(1024 / 32, 5632 / 32), tblk, 0, stream>>>(dw2, dw2t, 1024);
        transconv_moe_k<<<dim3(1024 / 32, 5632 / 32), tblk, 0, stream>>>(dw3, dw3t, 1024);
        transconv_moe_k<<<dim3(512 / 32, 5632 / 32), tblk, 0, stream>>>(dw4, dw4t, 512);
    } else {
        transconv_k<<<dim3(1024 / 32, 5632 / 32), tblk, 0, stream>>>(dw1, dw1t, 5632, 1024, 5632);
        transconv_k<<<dim3(1024 / 32, 5632 / 32), tblk, 0, stream>>>(dw2, dw2t, 5632, 1024, 5632);
        transconv_k<<<dim3(1024 / 32, 5632 / 32), tblk, 0, stream>>>(dw3, dw3t, 5632, 1024, 5632);
        transconv_k<<<dim3(512 / 32, 5632 / 32), tblk, 0, stream>>>(dw4, dw4t, 5632, 512, 5632);
    }

    // ---- normalize into cat buffers ----
    norm_k<<<dim3(BATCH * 768 / 256), blk, 0, stream>>>(x, w, rim, riv, rcm, rcv,
                                                        enc0, encA, encB, dec0);

    // ---- encoder ----
    dim3 gEnc(1024 / 128, BATCH / 128);
    mm_k<128, 128, 0><<<gEnc, blk, 0, stream>>>(enc0, 768, ew0t, 768, eb0, nullptr, nullptr,
                                                encA + 256, nullptr, nullptr, 1280, 1024, 768);
    mm_k<128, 128, 0><<<gEnc, blk, 0, stream>>>(encA, 1280, ew1t, 1280, eb1, nullptr, nullptr,
                                                encB + 256, nullptr, nullptr, 1280, 1024, 1280);
    mm_k<128, 128, 0><<<gEnc, blk, 0, stream>>>(encB, 1280, ew2t, 1280, eb2, nullptr, nullptr,
                                                encA + 256, nullptr, nullptr, 1280, 1024, 1280);
    mm_k<128, 128, 1><<<gEnc, blk, 0, stream>>>(encA, 1280, ew3t, 1280, eb3, nullptr, nullptr,
                                                hl, nullptr, nullptr, 1024, 1024, 1280);

    // ---- heads: mu | clip(lv) ----
    mm_k<64, 128, 2><<<dim3(2, BATCH / 64), blk, 0, stream>>>(hl, 1024, hdWt, 1024, mub, lvb,
                                                              nullptr, nullptr, mu_out, lv_out,
                                                              0, 256, 1024);

    reparam_k<<<dim3(BATCH * 128 / 256), blk, 0, stream>>>(mu_out, lv_out, epsv, z_out, dec0);

    // ---- gate ----
    mm_k<64, 64, 1><<<dim3(1, BATCH / 64), blk, 0, stream>>>(dec0, 384, gw0t, 384, gb0, nullptr,
                                                             nullptr, g0, nullptr, nullptr,
                                                             64, 64, 384);
    mm_k<64, 64, 1><<<dim3(1, BATCH / 64), blk, 0, stream>>>(g0, 64, gw1t, 64, gb1, nullptr,
                                                             nullptr, g1, nullptr, nullptr,
                                                             64, 64, 64);
    gate_sm_k<<<dim3(BATCH / 256), blk, 0, stream>>>(g1, gw2, gb2, cf);

    dim3 gDec(1024 / 128, BATCH / 128);
    if (fast) {
        // ---- FAST decoder: single GEMM per layer over grouped-scaled A' ----
        fill_zc_k<<<dim3(BATCH * 1536 / 256), blk, 0, stream>>>(dec0, cf, dAp, dBp);
        // dec0: reads dAp[:,0:1536), writes dAp[:,1536:) (disjoint columns, no race)
        mm_k<128, 128, 5><<<gDec, blk, 0, stream>>>(dAp, 5632, dw0t, 1536, db0, nullptr, cf,
                                                    dAp + 1536, nullptr, nullptr, 5632, 1024, 1536);
        mm_k<128, 128, 5><<<gDec, blk, 0, stream>>>(dAp, 5632, dw1t, 5632, db1, nullptr, cf,
                                                    dBp + 1536, nullptr, nullptr, 5632, 1024, 5632);
        mm_k<128, 128, 5><<<gDec, blk, 0, stream>>>(dBp, 5632, dw2t, 5632, db2, nullptr, cf,
                                                    dAp + 1536, nullptr, nullptr, 5632, 1024, 5632);
        mm_k<128, 128, 5><<<gDec, blk, 0, stream>>>(dAp, 5632, dw3t, 5632, db3, nullptr, cf,
                                                    dBp + 1536, nullptr, nullptr, 5632, 1024, 5632);
        mm_k<128, 128, 6><<<dim3(512 / 128, BATCH / 128), blk, 0, stream>>>(
            dBp, 5632, dw4t, 5632, db4, nullptr, cf, nullptr, y_out, nullptr, 512, 512, 5632);
    } else {
        // ---- SAFE decoder: expert-loop kernels (round-2 structure) ----
        fill_dec_k<<<dim3(BATCH * 384 / 256), blk, 0, stream>>>(dec0, decA, decB);
        mm_k<128, 128, 3><<<gDec, blk, 0, stream>>>(dec0, 384, dw0t, 1536, db0, nullptr, cf,
                                                    decA + 384, nullptr, nullptr, 1408, 1024, 384);
        mm_k<128, 128, 3><<<gDec, blk, 0, stream>>>(decA, 1408, dw1t, 5632, db1, nullptr, cf,
                                                    decB + 384, nullptr, nullptr, 1408, 1024, 1408);
        mm_k<128, 128, 3><<<gDec, blk, 0, stream>>>(decB, 1408, dw2t, 5632, db2, nullptr, cf,
                                                    decA + 384, nullptr, nullptr, 1408, 1024, 1408);
        mm_k<128, 128, 3><<<gDec, blk, 0, stream>>>(decA, 1408, dw3t, 5632, db3, nullptr, cf,
                                                    decB + 384, nullptr, nullptr, 1408, 1024, 1408);
        mm_k<128, 128, 4><<<dim3(512 / 128, BATCH / 128), blk, 0, stream>>>(
            decB, 1408, dw4t, 5632, db4, nullptr, cf, nullptr, y_out, nullptr, 512, 512, 1408);
    }
}

// Round 4
// 975.531 us; speedup vs baseline: 8.7653x; 1.1945x over previous
//
#include <hip/hip_runtime.h>

#define BATCH 8192

typedef __bf16 bf16x8 __attribute__((ext_vector_type(8)));
typedef float f32x4 __attribute__((ext_vector_type(4)));

__device__ __forceinline__ float leakyf(float x) { return x > 0.f ? x : 0.01f * x; }

__device__ __forceinline__ short f2bf(float f) {
    union { float f; unsigned u; } v; v.f = f;
    unsigned r = v.u + 0x7fffu + ((v.u >> 16) & 1u);  // RNE
    return (short)(r >> 16);
}
__device__ __forceinline__ float bf2f(short s) {
    union { unsigned u; float f; } v; v.u = ((unsigned)(unsigned short)s) << 16;
    return v.f;
}

// ---------------------------------------------------------------------------
// transpose + fp32->bf16 convert: out[c*ldo + r] = bf16(in[r*C + c])
// ---------------------------------------------------------------------------
__global__ __launch_bounds__(256) void transconv_k(const float* __restrict__ in,
                                                   short* __restrict__ out,
                                                   int R, int C, int ldo) {
    __shared__ float t[32][33];
    const int r0 = blockIdx.y * 32, c0 = blockIdx.x * 32;
    const int tx = threadIdx.x, ty = threadIdx.y;
#pragma unroll
    for (int i = 0; i < 4; ++i)
        t[ty * 4 + i][tx] = in[(size_t)(r0 + ty * 4 + i) * C + c0 + tx];
    __syncthreads();
#pragma unroll
    for (int i = 0; i < 4; ++i)
        out[(size_t)(c0 + ty * 4 + i) * ldo + r0 + tx] = f2bf(t[tx][ty * 4 + i]);
}

// ---------------------------------------------------------------------------
// MoE weight transpose with row permutation for the grouped-A' layout:
// input rows r = e*1408 + k; output col r' = k<384 ? e*384+k : 1536+e*1024+(k-384)
// ---------------------------------------------------------------------------
__global__ __launch_bounds__(256) void transconv_moe_k(const float* __restrict__ in,
                                                       short* __restrict__ out, int C) {
    __shared__ float t[32][33];
    const int r0 = blockIdx.y * 32, c0 = blockIdx.x * 32;
    const int tx = threadIdx.x, ty = threadIdx.y;
#pragma unroll
    for (int i = 0; i < 4; ++i)
        t[ty * 4 + i][tx] = in[(size_t)(r0 + ty * 4 + i) * C + c0 + tx];
    __syncthreads();
    const int e = r0 / 1408, k = r0 - e * 1408;
    const int rp0 = (k < 384) ? (e * 384 + k) : (1536 + e * 1024 + (k - 384));
#pragma unroll
    for (int i = 0; i < 4; ++i)
        out[(size_t)(c0 + ty * 4 + i) * 5632 + rp0 + tx] = f2bf(t[tx][ty * 4 + i]);
}

// ---------------------------------------------------------------------------
// bf16 MFMA GEMM: XCD swizzle + LDS XOR-swizzle (pre-swizzled global source,
// rule #21) + double-buffered 2-phase prefetch pipeline (T3 minimal recipe).
// EPI: 0 = +bias -> bf16      1 = +bias, leaky -> bf16
//      2 = heads mu|lv (N=256): col<128 -> f32 Cf; col>=128 clip -> f32 Cf2
//      3 = MoE expert loop, leaky -> bf16 (SAFE)   4 = same, no act -> f32
//      5 = +coeff@bias, leaky, 4 coeff-scaled bf16 copies (FAST)
//      6 = +coeff@bias, no act -> f32 (FAST last layer)
// ---------------------------------------------------------------------------
template <int BM, int BN, int EPI>
__global__ __launch_bounds__(256) void mm_k(
    const short* __restrict__ A, int lda,
    const short* __restrict__ Bt, int ldb,
    const float* __restrict__ bias, const float* __restrict__ bias2,
    const float* __restrict__ coeff,
    short* __restrict__ Cb, float* __restrict__ Cf, float* __restrict__ Cf2,
    int ldc, int N, int K) {
    constexpr bool MOE = (EPI == 3 || EPI == 4);
    constexpr int WM = BM / 2, WN = BN / 2;
    constexpr int FM = WM / 16, FN = WN / 16;
    constexpr int ASZ = BM * 64, BSZ = BN * 64;  // shorts per LDS half
    __shared__ short As[2 * ASZ];
    __shared__ short Bs[2 * BSZ];
    const int tid = threadIdx.x;
    const int wave = tid >> 6, lane = tid & 63;
    const int wm = wave >> 1, wq = wave & 1;

    // XCD-aware swizzle (bijective when nwg%8==0)
    int bx = blockIdx.x, by = blockIdx.y;
    {
        int nwg = gridDim.x * gridDim.y;
        if ((nwg & 7) == 0) {
            int flat = by * gridDim.x + bx;
            int nf = (flat & 7) * (nwg >> 3) + (flat >> 3);
            bx = nf % gridDim.x;
            by = nf / gridDim.x;
        }
    }
    const int m0 = by * BM, n0 = bx * BN;
    const int srow = lane >> 3;                             // 0..7
    const int scolsw = ((lane & 7) ^ srow) << 3;            // swizzled source col (shorts)
    const int l15 = lane & 15;
    const int khalf = (lane >> 4) << 3;                     // 0,8,16,24 shorts

    // stage one K-step (64 shorts/row) of A and B into LDS half `half`,
    // source column pre-swizzled so a linear LDS write yields XOR-swizzled tiles
    auto stage = [&](const short* Bsrc, int kt, int half) {
#pragma unroll
        for (int it = 0; it < BM / 32; ++it) {
            int chunk = it * 4 + wave;
            int row = chunk * 8 + srow;
            const short* g = A + (size_t)(m0 + row) * lda + kt + scolsw;
            __builtin_amdgcn_global_load_lds(
                (const __attribute__((address_space(1))) void*)g,
                (__attribute__((address_space(3))) void*)(As + half * ASZ + chunk * 512),
                16, 0, 0);
        }
#pragma unroll
        for (int it = 0; it < BN / 32; ++it) {
            int chunk = it * 4 + wave;
            int row = chunk * 8 + srow;
            const short* g = Bsrc + (size_t)(n0 + row) * ldb + kt + scolsw;
            __builtin_amdgcn_global_load_lds(
                (const __attribute__((address_space(1))) void*)g,
                (__attribute__((address_space(3))) void*)(Bs + half * BSZ + chunk * 512),
                16, 0, 0);
        }
    };

    f32x4 acc[FM][FN];
    f32x4 accf[MOE ? FM : 1][MOE ? FN : 1];
    const f32x4 z4 = {0.f, 0.f, 0.f, 0.f};
    if constexpr (MOE) {
#pragma unroll
        for (int i = 0; i < FM; ++i)
#pragma unroll
            for (int j = 0; j < FN; ++j) accf[i][j] = z4;
    }

    constexpr int NE = MOE ? 4 : 1;
    const int nk = K >> 6;
#pragma unroll 1
    for (int e = 0; e < NE; ++e) {
        const short* Be = Bt + (size_t)e * K;
#pragma unroll
        for (int i = 0; i < FM; ++i)
#pragma unroll
            for (int j = 0; j < FN; ++j) acc[i][j] = z4;

        stage(Be, 0, 0);      // prologue: tile 0 into half 0
        __syncthreads();      // drains vmcnt -> tile 0 ready

#pragma unroll 1
        for (int t = 0; t < nk; ++t) {
            const int cur = t & 1;
            if (t + 1 < nk) stage(Be, (t + 1) << 6, cur ^ 1);  // prefetch in flight over compute
            const short* Ah = As + cur * ASZ;
            const short* Bh = Bs + cur * BSZ;
#pragma unroll
            for (int kk = 0; kk < 2; ++kk) {
                bf16x8 a[FM], b[FN];
#pragma unroll
                for (int i = 0; i < FM; ++i) {
                    int R = wm * WM + i * 16 + l15;
                    int off = (kk * 32 + khalf) ^ ((R & 7) << 3);
                    a[i] = *(const bf16x8*)&Ah[R * 64 + off];
                }
#pragma unroll
                for (int j = 0; j < FN; ++j) {
                    int R = wq * WN + j * 16 + l15;
                    int off = (kk * 32 + khalf) ^ ((R & 7) << 3);
                    b[j] = *(const bf16x8*)&Bh[R * 64 + off];
                }
#pragma unroll
                for (int i = 0; i < FM; ++i)
#pragma unroll
                    for (int j = 0; j < FN; ++j)
                        acc[i][j] = __builtin_amdgcn_mfma_f32_16x16x32_bf16(
                            a[i], b[j], acc[i][j], 0, 0, 0);
            }
            __syncthreads();  // drains vmcnt (prefetch landed under compute) + read fence
        }
        if constexpr (MOE) {
#pragma unroll
            for (int i = 0; i < FM; ++i) {
                int rbase = m0 + wm * WM + i * 16 + ((lane >> 4) << 2);
#pragma unroll
                for (int r = 0; r < 4; ++r) {
                    float ce = coeff[(size_t)(rbase + r) * 4 + e];
#pragma unroll
                    for (int j = 0; j < FN; ++j) accf[i][j][r] += ce * acc[i][j][r];
                }
            }
        }
    }

    // epilogue: D layout col=lane&15, row=(lane>>4)*4+reg
#pragma unroll
    for (int i = 0; i < FM; ++i) {
#pragma unroll
        for (int r = 0; r < 4; ++r) {
            int row = m0 + wm * WM + i * 16 + ((lane >> 4) << 2) + r;
#pragma unroll
            for (int j = 0; j < FN; ++j) {
                int col = n0 + wq * WN + j * 16 + l15;
                float v = MOE ? accf[i][j][r] : acc[i][j][r];
                if constexpr (EPI == 0) {
                    v += bias[col];
                    Cb[(size_t)row * ldc + col] = f2bf(v);
                } else if constexpr (EPI == 1) {
                    v = leakyf(v + bias[col]);
                    Cb[(size_t)row * ldc + col] = f2bf(v);
                } else if constexpr (EPI == 2) {
                    if (col < 128) {
                        Cf[(size_t)row * 128 + col] = v + bias[col];
                    } else {
                        float u = v + bias2[col - 128];
                        u = fminf(fmaxf(u, -5.f), 5.f);
                        Cf2[(size_t)row * 128 + (col - 128)] = u;
                    }
                } else if constexpr (EPI == 3) {
                    const float* c4 = coeff + (size_t)row * 4;
                    v += c4[0] * bias[col] + c4[1] * bias[N + col] +
                         c4[2] * bias[2 * N + col] + c4[3] * bias[3 * N + col];
                    Cb[(size_t)row * ldc + col] = f2bf(leakyf(v));
                } else if constexpr (EPI == 4) {
                    const float* c4 = coeff + (size_t)row * 4;
                    v += c4[0] * bias[col] + c4[1] * bias[N + col] +
                         c4[2] * bias[2 * N + col] + c4[3] * bias[3 * N + col];
                    Cf[(size_t)row * ldc + col] = v;
                } else if constexpr (EPI == 5) {
                    const float4 c4 = *reinterpret_cast<const float4*>(coeff + (size_t)row * 4);
                    v += c4.x * bias[col] + c4.y * bias[N + col] +
                         c4.z * bias[2 * N + col] + c4.w * bias[3 * N + col];
                    float a = leakyf(v);
                    Cb[(size_t)row * ldc + 0 * 1024 + col] = f2bf(c4.x * a);
                    Cb[(size_t)row * ldc + 1 * 1024 + col] = f2bf(c4.y * a);
                    Cb[(size_t)row * ldc + 2 * 1024 + col] = f2bf(c4.z * a);
                    Cb[(size_t)row * ldc + 3 * 1024 + col] = f2bf(c4.w * a);
                } else {  // EPI == 6
                    const float4 c4 = *reinterpret_cast<const float4*>(coeff + (size_t)row * 4);
                    v += c4.x * bias[col] + c4.y * bias[N + col] +
                         c4.z * bias[2 * N + col] + c4.w * bias[3 * N + col];
                    Cf[(size_t)row * ldc + col] = v;
                }
            }
        }
    }
}

// ---------------------------------------------------------------------------
// normalize + scatter bf16 into cat buffers
// ---------------------------------------------------------------------------
__global__ __launch_bounds__(256) void norm_k(
    const float* __restrict__ x, const float* __restrict__ w,
    const float* __restrict__ im, const float* __restrict__ iv,
    const float* __restrict__ cm, const float* __restrict__ cv,
    short* __restrict__ enc0, short* __restrict__ encA,
    short* __restrict__ encB, short* __restrict__ dec0) {
    int idx = blockIdx.x * 256 + threadIdx.x;
    const int TX = BATCH * 512;
    if (idx < TX) {
        int b = idx >> 9, j = idx & 511;
        float v = (x[idx] - im[j]) * rsqrtf(iv[j] + 1e-4f);
        v = fminf(fmaxf(v, -5.f), 5.f);
        enc0[(size_t)b * 768 + j] = f2bf(v);
    } else {
        int k = idx - TX;
        if (k < BATCH * 256) {
            int b = k >> 8, j = k & 255;
            float v = (w[k] - cm[j]) * rsqrtf(cv[j] + 1e-4f);
            if (v != v) v = 0.f;  // isnan -> 0 (wn only)
            v = fminf(fmaxf(v, -5.f), 5.f);
            short s = f2bf(v);
            enc0[(size_t)b * 768 + 512 + j] = s;
            encA[(size_t)b * 1280 + j] = s;
            encB[(size_t)b * 1280 + j] = s;
            dec0[(size_t)b * 384 + 128 + j] = s;
        }
    }
}

__global__ __launch_bounds__(256) void reparam_k(
    const float* __restrict__ mu, const float* __restrict__ lv,
    const float* __restrict__ eps, float* __restrict__ z, short* __restrict__ dec0) {
    int idx = blockIdx.x * 256 + threadIdx.x;
    if (idx >= BATCH * 128) return;
    float zv = mu[idx] + eps[idx] * expf(0.5f * lv[idx]);
    z[idx] = zv;
    int b = idx >> 7, j = idx & 127;
    dec0[(size_t)b * 384 + j] = f2bf(zv);
}

// FAST: fill the static coeff-scaled [z|c] region (cols 0..1535) of both A' buffers
__global__ __launch_bounds__(256) void fill_zc_k(const short* __restrict__ dec0,
                                                 const float* __restrict__ cf,
                                                 short* __restrict__ dA,
                                                 short* __restrict__ dB) {
    int idx = blockIdx.x * 256 + threadIdx.x;
    if (idx >= BATCH * 1536) return;
    int b = idx / 1536, c = idx - b * 1536;
    int e = c / 384, k = c - e * 384;
    short s = f2bf(cf[(size_t)b * 4 + e] * bf2f(dec0[(size_t)b * 384 + k]));
    dA[(size_t)b * 5632 + c] = s;
    dB[(size_t)b * 5632 + c] = s;
}

// SAFE: replicate dec0 into the 1408-wide cat buffers
__global__ __launch_bounds__(256) void fill_dec_k(const short* __restrict__ dec0,
                                                  short* __restrict__ decA,
                                                  short* __restrict__ decB) {
    int idx = blockIdx.x * 256 + threadIdx.x;
    if (idx >= BATCH * 384) return;
    int b = idx / 384, c = idx - b * 384;
    short s = dec0[idx];
    decA[(size_t)b * 1408 + c] = s;
    decB[(size_t)b * 1408 + c] = s;
}

__global__ __launch_bounds__(256) void gate_sm_k(const short* __restrict__ g1,
                                                 const float* __restrict__ w2,
                                                 const float* __restrict__ b2,
                                                 float* __restrict__ coeff) {
    int r = blockIdx.x * 256 + threadIdx.x;
    if (r >= BATCH) return;
    float l0 = b2[0], l1 = b2[1], l2 = b2[2], l3 = b2[3];
    const short* row = g1 + (size_t)r * 64;
#pragma unroll
    for (int k = 0; k < 64; ++k) {
        float gv = bf2f(row[k]);
        l0 += gv * w2[k * 4 + 0];
        l1 += gv * w2[k * 4 + 1];
        l2 += gv * w2[k * 4 + 2];
        l3 += gv * w2[k * 4 + 3];
    }
    float mx = fmaxf(fmaxf(l0, l1), fmaxf(l2, l3));
    float e0 = expf(l0 - mx), e1 = expf(l1 - mx), e2 = expf(l2 - mx), e3 = expf(l3 - mx);
    float s = 1.f / (e0 + e1 + e2 + e3);
    float4 outv = make_float4(e0 * s, e1 * s, e2 * s, e3 * s);
    *reinterpret_cast<float4*>(coeff + (size_t)r * 4) = outv;
}

extern "C" void kernel_launch(void* const* d_in, const int* in_sizes, int n_in,
                              void* d_out, int out_size, void* d_ws, size_t ws_size,
                              hipStream_t stream) {
    const float* x    = (const float*)d_in[0];
    const float* w    = (const float*)d_in[1];
    const float* epsv = (const float*)d_in[2];
    const float* rim  = (const float*)d_in[3];
    const float* riv  = (const float*)d_in[4];
    const float* rcm  = (const float*)d_in[5];
    const float* rcv  = (const float*)d_in[6];
    const float* ew0 = (const float*)d_in[7];  const float* eb0 = (const float*)d_in[8];
    const float* ew1 = (const float*)d_in[9];  const float* eb1 = (const float*)d_in[10];
    const float* ew2 = (const float*)d_in[11]; const float* eb2 = (const float*)d_in[12];
    const float* ew3 = (const float*)d_in[13]; const float* eb3 = (const float*)d_in[14];
    const float* muw = (const float*)d_in[15]; const float* mub = (const float*)d_in[16];
    const float* lvw = (const float*)d_in[17]; const float* lvb = (const float*)d_in[18];
    const float* gw0 = (const float*)d_in[19]; const float* gb0 = (const float*)d_in[20];
    const float* gw1 = (const float*)d_in[21]; const float* gb1 = (const float*)d_in[22];
    const float* gw2 = (const float*)d_in[23]; const float* gb2 = (const float*)d_in[24];
    const float* dw0 = (const float*)d_in[25]; const float* db0 = (const float*)d_in[26];
    const float* dw1 = (const float*)d_in[27]; const float* db1 = (const float*)d_in[28];
    const float* dw2 = (const float*)d_in[29]; const float* db2 = (const float*)d_in[30];
    const float* dw3 = (const float*)d_in[31]; const float* db3 = (const float*)d_in[32];
    const float* dw4 = (const float*)d_in[33]; const float* db4 = (const float*)d_in[34];

    float* out    = (float*)d_out;
    float* z_out  = out;                          // [B,128]
    float* y_out  = out + (size_t)BATCH * 128;    // [B,512]
    float* mu_out = out + (size_t)BATCH * 640;    // [B,128]
    float* lv_out = out + (size_t)BATCH * 768;    // [B,128]

    // ---- workspace carve ----
    char* cur = (char*)d_ws;
    auto alloc = [&](size_t bytes) -> char* {
        char* p = cur;
        cur += (bytes + 255) & ~(size_t)255;
        return p;
    };
    auto align256 = [](size_t b) { return (b + 255) & ~(size_t)255; };

    short* ew0t = (short*)alloc((size_t)768 * 1024 * 2);
    short* ew1t = (short*)alloc((size_t)1280 * 1024 * 2);
    short* ew2t = (short*)alloc((size_t)1280 * 1024 * 2);
    short* ew3t = (short*)alloc((size_t)1280 * 1024 * 2);
    short* hdWt = (short*)alloc((size_t)256 * 1024 * 2);   // rows 0-127 mu, 128-255 lv
    short* gw0t = (short*)alloc((size_t)64 * 384 * 2);
    short* gw1t = (short*)alloc((size_t)64 * 64 * 2);
    short* dw0t = (short*)alloc((size_t)1024 * 1536 * 2);
    short* dw1t = (short*)alloc((size_t)1024 * 5632 * 2);
    short* dw2t = (short*)alloc((size_t)1024 * 5632 * 2);
    short* dw3t = (short*)alloc((size_t)1024 * 5632 * 2);
    short* dw4t = (short*)alloc((size_t)512 * 5632 * 2);
    short* dec0 = (short*)alloc((size_t)BATCH * 384 * 2);  // [z|wn]
    short* g0   = (short*)alloc((size_t)BATCH * 64 * 2);
    short* g1   = (short*)alloc((size_t)BATCH * 64 * 2);
    float* cf   = (float*)alloc((size_t)BATCH * 4 * 4);

    char* region = cur;
    const size_t bigA = align256((size_t)BATCH * 5632 * 2);     // 92.3 MB
    const size_t fastNeed = (size_t)(region - (char*)d_ws) + 2 * bigA;
    const bool fast = (ws_size >= fastNeed);

    // encoder buffers (alias the decoder region; encoder finishes before decoder)
    short* enc0 = (short*)region;                                           // [B,768]
    short* encA = (short*)(region + align256((size_t)BATCH * 768 * 2));     // [B,1280]
    short* encB = (short*)((char*)encA + align256((size_t)BATCH * 1280 * 2)); // [B,1280]
    short* hl   = encB;                                                     // [B,1024]
    // FAST decoder A' ping-pong: [B][5632] = [zc(1536) | out-scaled(4096)]
    short* dAp = (short*)region;
    short* dBp = (short*)(region + bigA);
    // SAFE decoder cat buffers
    short* decA = (short*)region;                                           // [B,1408]
    short* decB = (short*)(region + align256((size_t)BATCH * 1408 * 2));    // [B,1408]

    dim3 blk(256);
    dim3 tblk(32, 8);

    // ---- weight transpose+convert ----
    transconv_k<<<dim3(1024 / 32, 768 / 32), tblk, 0, stream>>>(ew0, ew0t, 768, 1024, 768);
    transconv_k<<<dim3(1024 / 32, 1280 / 32), tblk, 0, stream>>>(ew1, ew1t, 1280, 1024, 1280);
    transconv_k<<<dim3(1024 / 32, 1280 / 32), tblk, 0, stream>>>(ew2, ew2t, 1280, 1024, 1280);
    transconv_k<<<dim3(1024 / 32, 1280 / 32), tblk, 0, stream>>>(ew3, ew3t, 1280, 1024, 1280);
    transconv_k<<<dim3(128 / 32, 1024 / 32), tblk, 0, stream>>>(muw, hdWt, 1024, 128, 1024);
    transconv_k<<<dim3(128 / 32, 1024 / 32), tblk, 0, stream>>>(lvw, hdWt + (size_t)128 * 1024, 1024, 128, 1024);
    transconv_k<<<dim3(64 / 32, 384 / 32), tblk, 0, stream>>>(gw0, gw0t, 384, 64, 384);
    transconv_k<<<dim3(64 / 32, 64 / 32), tblk, 0, stream>>>(gw1, gw1t, 64, 64, 64);
    transconv_k<<<dim3(1024 / 32, 1536 / 32), tblk, 0, stream>>>(dw0, dw0t, 1536, 1024, 1536);
    if (fast) {
        transconv_moe_k<<<dim3(1024 / 32, 5632 / 32), tblk, 0, stream>>>(dw1, dw1t, 1024);
        transconv_moe_k<<<dim3(1024 / 32, 5632 / 32), tblk, 0, stream>>>(dw2, dw2t, 1024);
        transconv_moe_k<<<dim3(1024 / 32, 5632 / 32), tblk, 0, stream>>>(dw3, dw3t, 1024);
        transconv_moe_k<<<dim3(512 / 32, 5632 / 32), tblk, 0, stream>>>(dw4, dw4t, 512);
    } else {
        transconv_k<<<dim3(1024 / 32, 5632 / 32), tblk, 0, stream>>>(dw1, dw1t, 5632, 1024, 5632);
        transconv_k<<<dim3(1024 / 32, 5632 / 32), tblk, 0, stream>>>(dw2, dw2t, 5632, 1024, 5632);
        transconv_k<<<dim3(1024 / 32, 5632 / 32), tblk, 0, stream>>>(dw3, dw3t, 5632, 1024, 5632);
        transconv_k<<<dim3(512 / 32, 5632 / 32), tblk, 0, stream>>>(dw4, dw4t, 5632, 512, 5632);
    }

    // ---- normalize into cat buffers ----
    norm_k<<<dim3(BATCH * 768 / 256), blk, 0, stream>>>(x, w, rim, riv, rcm, rcv,
                                                        enc0, encA, encB, dec0);

    // ---- encoder ----
    dim3 gEnc(1024 / 128, BATCH / 128);
    mm_k<128, 128, 0><<<gEnc, blk, 0, stream>>>(enc0, 768, ew0t, 768, eb0, nullptr, nullptr,
                                                encA + 256, nullptr, nullptr, 1280, 1024, 768);
    mm_k<128, 128, 0><<<gEnc, blk, 0, stream>>>(encA, 1280, ew1t, 1280, eb1, nullptr, nullptr,
                                                encB + 256, nullptr, nullptr, 1280, 1024, 1280);
    mm_k<128, 128, 0><<<gEnc, blk, 0, stream>>>(encB, 1280, ew2t, 1280, eb2, nullptr, nullptr,
                                                encA + 256, nullptr, nullptr, 1280, 1024, 1280);
    mm_k<128, 128, 1><<<gEnc, blk, 0, stream>>>(encA, 1280, ew3t, 1280, eb3, nullptr, nullptr,
                                                hl, nullptr, nullptr, 1024, 1024, 1280);

    // ---- heads: mu | clip(lv) ----
    mm_k<64, 128, 2><<<dim3(2, BATCH / 64), blk, 0, stream>>>(hl, 1024, hdWt, 1024, mub, lvb,
                                                              nullptr, nullptr, mu_out, lv_out,
                                                              0, 256, 1024);

    reparam_k<<<dim3(BATCH * 128 / 256), blk, 0, stream>>>(mu_out, lv_out, epsv, z_out, dec0);

    // ---- gate ----
    mm_k<64, 64, 1><<<dim3(1, BATCH / 64), blk, 0, stream>>>(dec0, 384, gw0t, 384, gb0, nullptr,
                                                             nullptr, g0, nullptr, nullptr,
                                                             64, 64, 384);
    mm_k<64, 64, 1><<<dim3(1, BATCH / 64), blk, 0, stream>>>(g0, 64, gw1t, 64, gb1, nullptr,
                                                             nullptr, g1, nullptr, nullptr,
                                                             64, 64, 64);
    gate_sm_k<<<dim3(BATCH / 256), blk, 0, stream>>>(g1, gw2, gb2, cf);

    dim3 gDec(1024 / 128, BATCH / 128);
    if (fast) {
        // ---- FAST decoder: single GEMM per layer over grouped-scaled A' ----
        fill_zc_k<<<dim3(BATCH * 1536 / 256), blk, 0, stream>>>(dec0, cf, dAp, dBp);
        mm_k<128, 128, 5><<<gDec, blk, 0, stream>>>(dAp, 5632, dw0t, 1536, db0, nullptr, cf,
                                                    dAp + 1536, nullptr, nullptr, 5632, 1024, 1536);
        mm_k<128, 128, 5><<<gDec, blk, 0, stream>>>(dAp, 5632, dw1t, 5632, db1, nullptr, cf,
                                                    dBp + 1536, nullptr, nullptr, 5632, 1024, 5632);
        mm_k<128, 128, 5><<<gDec, blk, 0, stream>>>(dBp, 5632, dw2t, 5632, db2, nullptr, cf,
                                                    dAp + 1536, nullptr, nullptr, 5632, 1024, 5632);
        mm_k<128, 128, 5><<<gDec, blk, 0, stream>>>(dAp, 5632, dw3t, 5632, db3, nullptr, cf,
                                                    dBp + 1536, nullptr, nullptr, 5632, 1024, 5632);
        mm_k<128, 128, 6><<<dim3(512 / 128, BATCH / 128), blk, 0, stream>>>(
            dBp, 5632, dw4t, 5632, db4, nullptr, cf, nullptr, y_out, nullptr, 512, 512, 5632);
    } else {
        // ---- SAFE decoder: expert-loop kernels ----
        fill_dec_k<<<dim3(BATCH * 384 / 256), blk, 0, stream>>>(dec0, decA, decB);
        mm_k<128, 128, 3><<<gDec, blk, 0, stream>>>(dec0, 384, dw0t, 1536, db0, nullptr, cf,
                                                    decA + 384, nullptr, nullptr, 1408, 1024, 384);
        mm_k<128, 128, 3><<<gDec, blk, 0, stream>>>(decA, 1408, dw1t, 5632, db1, nullptr, cf,
                                                    decB + 384, nullptr, nullptr, 1408, 1024, 1408);
        mm_k<128, 128, 3><<<gDec, blk, 0, stream>>>(decB, 1408, dw2t, 5632, db2, nullptr, cf,
                                                    decA + 384, nullptr, nullptr, 1408, 1024, 1408);
        mm_k<128, 128, 3><<<gDec, blk, 0, stream>>>(decA, 1408, dw3t, 5632, db3, nullptr, cf,
                                                    decB + 384, nullptr, nullptr, 1408, 1024, 1408);
        mm_k<128, 128, 4><<<dim3(512 / 128, BATCH / 128), blk, 0, stream>>>(
            decB, 1408, dw4t, 5632, db4, nullptr, cf, nullptr, y_out, nullptr, 512, 512, 1408);
    }
}